// Round 1
// baseline (990.909 us; speedup 1.0000x reference)
//
#include <hip/hip_runtime.h>

// ---------------- kernels ----------------

__global__ void k_count(const int* __restrict__ dst, int* __restrict__ degi, int E) {
    int e = blockIdx.x * blockDim.x + threadIdx.x;
    if (e < E) atomicAdd(&degi[dst[e]], 1);
}

__global__ void k_dinv(const int* __restrict__ degi, float* __restrict__ dinv, int n) {
    int i = blockIdx.x * blockDim.x + threadIdx.x;
    if (i < n) dinv[i] = rsqrtf((float)(degi[i] + 1));  // +1 self loop; always > 0
}

// block-local exclusive scan of degi -> rowptr, block totals -> bsum
__global__ void k_scan1(const int* __restrict__ degi, int* __restrict__ rowptr,
                        int* __restrict__ bsum, int n) {
    __shared__ int s[256];
    int tid = threadIdx.x;
    int i = blockIdx.x * 256 + tid;
    int v = (i < n) ? degi[i] : 0;
    s[tid] = v;
    __syncthreads();
    for (int off = 1; off < 256; off <<= 1) {
        int t = (tid >= off) ? s[tid - off] : 0;
        __syncthreads();
        s[tid] += t;
        __syncthreads();
    }
    if (i < n) rowptr[i] = s[tid] - v;
    if (tid == 255) bsum[blockIdx.x] = s[255];
}

// single-block exclusive scan of block sums (nb <= 512)
__global__ void k_scan2(int* __restrict__ bsum, int nb) {
    __shared__ int s[512];
    int tid = threadIdx.x;
    int v = (tid < nb) ? bsum[tid] : 0;
    s[tid] = v;
    __syncthreads();
    for (int off = 1; off < 512; off <<= 1) {
        int t = (tid >= off) ? s[tid - off] : 0;
        __syncthreads();
        s[tid] += t;
        __syncthreads();
    }
    if (tid < nb) bsum[tid] = s[tid] - v;
}

__global__ void k_scan3(int* __restrict__ rowptr, int* __restrict__ cursor,
                        const int* __restrict__ bsum, int n, int total) {
    int i = blockIdx.x * blockDim.x + threadIdx.x;
    if (i < n) {
        int r = rowptr[i] + bsum[i >> 8];
        rowptr[i] = r;
        cursor[i] = r;
    }
    if (i == 0) rowptr[n] = total;
}

__global__ void k_fill(const int* __restrict__ src, const int* __restrict__ dst,
                       int* __restrict__ cursor, int* __restrict__ col, int E) {
    int e = blockIdx.x * blockDim.x + threadIdx.x;
    if (e < E) {
        int d = dst[e];
        int p = atomicAdd(&cursor[d], 1);
        col[p] = src[e];
    }
}

// h[n][j] = sum_k x[n][k] * emb_w[j][k] + emb_b[j]   (in_f = 4)
__global__ void k_embed(const float* __restrict__ x, const float* __restrict__ w,
                        const float* __restrict__ b, float* __restrict__ h, int n) {
    int idx = blockIdx.x * blockDim.x + threadIdx.x;
    if (idx >= n * 64) return;
    int node = idx >> 6, j = idx & 63;
    float4 xv = *(const float4*)(x + node * 4);
    float4 wv = *(const float4*)(w + j * 4);
    float s = b[j];
    s = fmaf(xv.x, wv.x, s);
    s = fmaf(xv.y, wv.y, s);
    s = fmaf(xv.z, wv.z, s);
    s = fmaf(xv.w, wv.w, s);
    h[idx] = s;
}

// u = (h @ W^T) * dinv[node] ; 64-node tile per block, 4x4x4 register blocking
__global__ __launch_bounds__(256) void k_gemm(const float* __restrict__ hin,
                                              const float* __restrict__ W,
                                              const float* __restrict__ dinv,
                                              float* __restrict__ uout, int n) {
    __shared__ float hN[64 * 68];  // [node][k], stride 68 (16B-aligned rows, conflict-free)
    __shared__ float wT[64 * 68];  // [k][j]
    int tid = threadIdx.x;
    int nbase = blockIdx.x * 64;
    for (int i = tid; i < 4096; i += 256) {
        int j = i >> 6, k = i & 63;
        wT[k * 68 + j] = W[i];
    }
    for (int i = tid; i < 4096; i += 256) {
        int nn = i >> 6, k = i & 63;
        int node = nbase + nn;
        hN[nn * 68 + k] = (node < n) ? hin[node * 64 + k] : 0.f;
    }
    __syncthreads();

    int tx = tid & 15;  // j0 = tx*4
    int ty = tid >> 4;  // n0 = ty*4
    float acc[4][4] = {};
#pragma unroll
    for (int k0 = 0; k0 < 64; k0 += 4) {
        float a[4][4], w[4][4];
#pragma unroll
        for (int i = 0; i < 4; i++)
            *(float4*)a[i] = *(const float4*)&hN[(ty * 4 + i) * 68 + k0];
#pragma unroll
        for (int dk = 0; dk < 4; dk++)
            *(float4*)w[dk] = *(const float4*)&wT[(k0 + dk) * 68 + tx * 4];
#pragma unroll
        for (int i = 0; i < 4; i++)
#pragma unroll
            for (int j = 0; j < 4; j++)
#pragma unroll
                for (int dk = 0; dk < 4; dk++)
                    acc[i][j] = fmaf(a[i][dk], w[dk][j], acc[i][j]);
    }
#pragma unroll
    for (int i = 0; i < 4; i++) {
        int node = nbase + ty * 4 + i;
        if (node < n) {
            float sc = dinv[node];
            float4 o;
            o.x = acc[i][0] * sc;
            o.y = acc[i][1] * sc;
            o.z = acc[i][2] * sc;
            o.w = acc[i][3] * sc;
            *(float4*)&uout[node * 64 + tx * 4] = o;
        }
    }
}

// one wave per node: h[n] = relu(dinv[n] * (u[n] + sum_in u[s]) + bias)
__global__ void k_agg(const float* __restrict__ u, const int* __restrict__ rowptr,
                      const int* __restrict__ col, const float* __restrict__ dinv,
                      const float* __restrict__ bias, float* __restrict__ hout, int n) {
    int wid = (blockIdx.x * blockDim.x + threadIdx.x) >> 6;
    int lane = threadIdx.x & 63;
    if (wid >= n) return;
    float acc = u[(size_t)wid * 64 + lane];  // self loop term
    int p = rowptr[wid];
    int e = rowptr[wid + 1];
    for (; p + 4 <= e; p += 4) {
        int s0 = col[p], s1 = col[p + 1], s2 = col[p + 2], s3 = col[p + 3];
        float v0 = u[(size_t)s0 * 64 + lane];
        float v1 = u[(size_t)s1 * 64 + lane];
        float v2 = u[(size_t)s2 * 64 + lane];
        float v3 = u[(size_t)s3 * 64 + lane];
        acc += v0; acc += v1; acc += v2; acc += v3;
    }
    for (; p < e; p++) acc += u[(size_t)col[p] * 64 + lane];
    hout[(size_t)wid * 64 + lane] = fmaxf(fmaf(dinv[wid], acc, bias[lane]), 0.f);
}

// one wave per graph: mean pool (batch sorted, binary search) + MLP head
__global__ __launch_bounds__(256) void k_pool(const float* __restrict__ h,
                                              const int* __restrict__ batch,
                                              const float* __restrict__ l1w,
                                              const float* __restrict__ l1b,
                                              const float* __restrict__ l2w,
                                              const float* __restrict__ l2b,
                                              float* __restrict__ out, int n, int G) {
    __shared__ float wl[64 * 65];
    int tid = threadIdx.x;
    for (int i = tid; i < 4096; i += 256) {
        int j = i >> 6, k = i & 63;
        wl[j * 65 + k] = l1w[i];
    }
    __syncthreads();
    int g = blockIdx.x * 4 + (tid >> 6);
    int lane = tid & 63;
    if (g >= G) return;

    int lo = 0, hi = n;
    while (lo < hi) { int mid = (lo + hi) >> 1; if (batch[mid] < g) lo = mid + 1; else hi = mid; }
    int start = lo;
    hi = n;
    while (lo < hi) { int mid = (lo + hi) >> 1; if (batch[mid] < g + 1) lo = mid + 1; else hi = mid; }
    int end = lo;

    float acc = 0.f;
    int node = start;
    for (; node + 4 <= end; node += 4) {
        float v0 = h[(size_t)(node + 0) * 64 + lane];
        float v1 = h[(size_t)(node + 1) * 64 + lane];
        float v2 = h[(size_t)(node + 2) * 64 + lane];
        float v3 = h[(size_t)(node + 3) * 64 + lane];
        acc += v0; acc += v1; acc += v2; acc += v3;
    }
    for (; node < end; node++) acc += h[(size_t)node * 64 + lane];
    float cnt = (float)((end - start) > 0 ? (end - start) : 1);
    float gm = acc / cnt;

    float pj = l1b[lane];
#pragma unroll
    for (int k = 0; k < 64; k++) pj = fmaf(__shfl(gm, k, 64), wl[lane * 65 + k], pj);
    pj = fmaxf(pj, 0.f);

    for (int o = 0; o < 3; o++) {
        float v = pj * l2w[o * 64 + lane];
        for (int off = 32; off; off >>= 1) v += __shfl_xor(v, off, 64);
        if (lane == 0) out[g * 3 + o] = v + l2b[o];
    }
}

// ---------------- launch ----------------

extern "C" void kernel_launch(void* const* d_in, const int* in_sizes, int n_in,
                              void* d_out, int out_size, void* d_ws, size_t ws_size,
                              hipStream_t stream) {
    const float* x      = (const float*)d_in[0];
    const int*   edge   = (const int*)d_in[1];
    const int*   batch  = (const int*)d_in[2];
    const float* emb_w  = (const float*)d_in[3];
    const float* emb_b  = (const float*)d_in[4];
    const float* conv_w = (const float*)d_in[5];
    const float* conv_b = (const float*)d_in[6];
    const float* l1w    = (const float*)d_in[7];
    const float* l1b    = (const float*)d_in[8];
    const float* l2w    = (const float*)d_in[9];
    const float* l2b    = (const float*)d_in[10];
    float* out = (float*)d_out;

    const int N = in_sizes[2];      // 100000 nodes
    const int E = in_sizes[1] / 2;  // 3200000 edges
    const int G = out_size / 3;     // 2000 graphs

    char* ws = (char*)d_ws;
    size_t off = 0;
    auto alloc = [&](size_t bytes) -> void* {
        void* p = ws + off;
        off = (off + bytes + 255) & ~(size_t)255;
        return p;
    };
    int*   degi   = (int*)alloc((size_t)N * 4);
    float* dinv   = (float*)alloc((size_t)N * 4);
    int*   rowptr = (int*)alloc((size_t)(N + 1) * 4);
    int*   cursor = (int*)alloc((size_t)N * 4);
    int*   bsum   = (int*)alloc(512 * 4);
    int*   colw   = (int*)alloc((size_t)E * 4);
    float* hbuf   = (float*)alloc((size_t)N * 64 * 4);
    float* ubuf   = (float*)alloc((size_t)N * 64 * 4);

    const int* esrc = edge;
    const int* edst = edge + E;

    hipMemsetAsync(degi, 0, (size_t)N * 4, stream);
    k_count<<<(E + 255) / 256, 256, 0, stream>>>(edst, degi, E);
    k_dinv<<<(N + 255) / 256, 256, 0, stream>>>(degi, dinv, N);
    int nb = (N + 255) / 256;  // 391 <= 512
    k_scan1<<<nb, 256, 0, stream>>>(degi, rowptr, bsum, N);
    k_scan2<<<1, 512, 0, stream>>>(bsum, nb);
    k_scan3<<<nb, 256, 0, stream>>>(rowptr, cursor, bsum, N, E);
    k_fill<<<(E + 255) / 256, 256, 0, stream>>>(esrc, edst, cursor, colw, E);

    k_embed<<<(N * 64 + 255) / 256, 256, 0, stream>>>(x, emb_w, emb_b, hbuf, N);

    for (int l = 0; l < 3; l++) {
        k_gemm<<<(N + 63) / 64, 256, 0, stream>>>(hbuf, conv_w + (size_t)l * 64 * 64, dinv, ubuf, N);
        k_agg<<<(N + 3) / 4, 256, 0, stream>>>(ubuf, rowptr, colw, dinv, conv_b + (size_t)l * 64, hbuf, N);
    }

    k_pool<<<(G + 3) / 4, 256, 0, stream>>>(hbuf, batch, l1w, l1b, l2w, l2b, out, N, G);
}